// Round 11
// baseline (1139.892 us; speedup 1.0000x reference)
//
#include <hip/hip_runtime.h>

#define B_   32
#define T_   300
#define C1_  2312
#define O1_  512
#define O2_  512
#define O3_  10
#define M_   (B_*T_)   // 9600

// ---------------- weight prep (all f64) ----------------

__global__ void calc_f(const float* __restrict__ v, const float* __restrict__ g,
                       double* __restrict__ f, int O, int C) {
    int o = blockIdx.x;
    const float* row = v + (size_t)o * C;
    double s = 0.0;
    for (int c = threadIdx.x; c < C; c += blockDim.x) {
        double x = (double)row[c];
        s += x * x;
    }
    for (int off = 32; off; off >>= 1) s += __shfl_down(s, off);
    __shared__ double wsum[4];
    int lane = threadIdx.x & 63, wv = threadIdx.x >> 6;
    if (lane == 0) wsum[wv] = s;
    __syncthreads();
    if (threadIdx.x == 0) {
        double tot = 0.0;
        for (int i = 0; i < (int)(blockDim.x >> 6); ++i) tot += wsum[i];
        f[o] = (double)g[o] / sqrt(tot);
    }
}

// wt[c*ldo + o] = v[o*C + c] * f[o]   (double)
__global__ void transpose_scale(const float* __restrict__ v, const double* __restrict__ f,
                                double* __restrict__ wt, int O, int C, int ldo) {
    __shared__ double tile[32][33];
    int c0 = blockIdx.x * 32, o0 = blockIdx.y * 32;
    int tx = threadIdx.x, ty = threadIdx.y;
    for (int k = 0; k < 4; ++k) {
        int o = o0 + ty + k * 8, c = c0 + tx;
        double val = 0.0;
        if (o < O && c < C) val = (double)v[(size_t)o * C + c] * f[o];
        tile[ty + k * 8][tx] = val;
    }
    __syncthreads();
    for (int k = 0; k < 4; ++k) {
        int c = c0 + ty + k * 8, o = o0 + tx;
        if (c < C && o < O) wt[(size_t)c * ldo + o] = tile[tx][ty + k * 8];
    }
}

// ---------------- GEMM layer 1 (f64, barrier-free, LDS-free, ballot-sparse) ----------------
// X: spike [B, C1, T] f32 (0/1) ; Wt: [C1, O1] f64 ; Z: [B, T, O1] f64
// Block = 256 thr = 4 INDEPENDENT waves (no barriers, no LDS). Wave w owns
// (b, t-octet t0+8w.., o-slice o0..o0+127). Lane l covers o = o0+lane(+64).
// Per 64-c chunk: lane l loads X[c0+l][octet] -> 8 __ballot u64 masks
// (wave-uniform). Inner loop visits ONLY set bits of any=|masks; W fragments
// loaded straight from global (lane-coalesced 512B, L2-resident), 2-stage
// pipelined. Adds ascend in c; only exact +w*0 terms elided -> bit-identical.
__global__ __launch_bounds__(256) void gemm1(const float* __restrict__ X,
                                             const double* __restrict__ Wt,
                                             double* __restrict__ Z) {
    int b  = blockIdx.z;
    int o0 = blockIdx.y * 128;
    int t0 = blockIdx.x * 32 + ((threadIdx.x >> 6) << 3);   // wave's t-octet
    int lane = threadIdx.x & 63;
    double acc[8][2];
#pragma unroll
    for (int t = 0; t < 8; ++t) { acc[t][0] = 0.0; acc[t][1] = 0.0; }
    const float* Xb = X + (size_t)b * C1_ * T_;
    const double* Wb = Wt + o0 + lane;

    for (int c0 = 0; c0 < C1_; c0 += 64) {
        // lane l: X[c0+l][t0..t0+7] (guarded)
        float xv[8];
        {
            int c = c0 + lane;
            float4 v0 = make_float4(0.f, 0.f, 0.f, 0.f);
            float4 v1 = make_float4(0.f, 0.f, 0.f, 0.f);
            if (c < C1_) {
                if (t0 < T_)     v0 = *(const float4*)(Xb + (size_t)c * T_ + t0);
                if (t0 + 4 < T_) v1 = *(const float4*)(Xb + (size_t)c * T_ + t0 + 4);
            }
            xv[0]=v0.x; xv[1]=v0.y; xv[2]=v0.z; xv[3]=v0.w;
            xv[4]=v1.x; xv[5]=v1.y; xv[6]=v1.z; xv[7]=v1.w;
        }
        unsigned long long m[8];
#pragma unroll
        for (int t = 0; t < 8; ++t) m[t] = __ballot(xv[t] != 0.f);
        unsigned long long any = ((m[0]|m[1])|(m[2]|m[3])) | ((m[4]|m[5])|(m[6]|m[7]));
        if (any) {
            int k = __builtin_ctzll(any); any &= any - 1;
            const double* wp = Wb + (size_t)(c0 + k) * O1_;
            double w0 = wp[0], w1 = wp[64];
            int kc = k;
            while (any) {
                int kn = __builtin_ctzll(any); any &= any - 1;
                const double* wpn = Wb + (size_t)(c0 + kn) * O1_;
                double n0 = wpn[0], n1 = wpn[64];   // overlaps with adds below
#pragma unroll
                for (int t = 0; t < 8; ++t)
                    if ((m[t] >> kc) & 1ull) { acc[t][0] += w0; acc[t][1] += w1; }
                kc = kn; w0 = n0; w1 = n1;
            }
#pragma unroll
            for (int t = 0; t < 8; ++t)
                if ((m[t] >> kc) & 1ull) { acc[t][0] += w0; acc[t][1] += w1; }
        }
    }
#pragma unroll
    for (int t = 0; t < 8; ++t) {
        int tg = t0 + t;
        if (tg < T_) {
            double* dst = Z + ((size_t)b * T_ + tg) * O1_ + o0 + lane;
            dst[0] = acc[t][0]; dst[64] = acc[t][1];
        }
    }
}

// ---------------- GEMM layer 2 (f64, same barrier-free ballot structure) ----------------
// A: s [M, 512] f32 (0/1) ; Wt: [512, 512] f64 ; Z: [M, 512] f64
// Wave owns (m-octet, 128-o slice). Lane l loads A[m_t][c0+l] (coalesced).
__global__ __launch_bounds__(256) void gemm2(const float* __restrict__ A,
                                             const double* __restrict__ Wt,
                                             double* __restrict__ Z) {
    int m0 = blockIdx.x * 32 + ((threadIdx.x >> 6) << 3);   // wave's m-octet
    int o0 = blockIdx.y * 128;
    int lane = threadIdx.x & 63;
    double acc[8][2];
#pragma unroll
    for (int t = 0; t < 8; ++t) { acc[t][0] = 0.0; acc[t][1] = 0.0; }
    const double* Wb = Wt + o0 + lane;

    for (int c0 = 0; c0 < 512; c0 += 64) {
        unsigned long long m[8];
#pragma unroll
        for (int t = 0; t < 8; ++t) {
            float a = A[(size_t)(m0 + t) * 512 + c0 + lane];
            m[t] = __ballot(a != 0.f);
        }
        unsigned long long any = ((m[0]|m[1])|(m[2]|m[3])) | ((m[4]|m[5])|(m[6]|m[7]));
        if (any) {
            int k = __builtin_ctzll(any); any &= any - 1;
            const double* wp = Wb + (size_t)(c0 + k) * 512;
            double w0 = wp[0], w1 = wp[64];
            int kc = k;
            while (any) {
                int kn = __builtin_ctzll(any); any &= any - 1;
                const double* wpn = Wb + (size_t)(c0 + kn) * 512;
                double n0 = wpn[0], n1 = wpn[64];
#pragma unroll
                for (int t = 0; t < 8; ++t)
                    if ((m[t] >> kc) & 1ull) { acc[t][0] += w0; acc[t][1] += w1; }
                kc = kn; w0 = n0; w1 = n1;
            }
#pragma unroll
            for (int t = 0; t < 8; ++t)
                if ((m[t] >> kc) & 1ull) { acc[t][0] += w0; acc[t][1] += w1; }
        }
    }
#pragma unroll
    for (int t = 0; t < 8; ++t) {
        double* dst = Z + (size_t)(m0 + t) * 512 + o0 + lane;
        dst[0] = acc[t][0]; dst[64] = acc[t][1];
    }
}

// ---------------- GEMM layer 3 (f64 acc) ----------------
__global__ __launch_bounds__(256) void gemm3(const float* __restrict__ A,
                                             const double* __restrict__ Wt,
                                             double* __restrict__ Z) {
    __shared__ double w[512 * 16];
    for (int e = threadIdx.x; e < 4096; e += 256)
        ((double2*)w)[e] = ((const double2*)Wt)[e];
    __syncthreads();
    int m = blockIdx.x * 256 + threadIdx.x;
    if (m >= M_) return;
    double acc[O3_];
#pragma unroll
    for (int o = 0; o < O3_; ++o) acc[o] = 0.0;
    const float4* Ar = (const float4*)(A + (size_t)m * 512);
    for (int cq = 0; cq < 128; ++cq) {
        float4 a = Ar[cq];
        float av[4] = {a.x, a.y, a.z, a.w};
#pragma unroll
        for (int u = 0; u < 4; ++u)
#pragma unroll
            for (int o = 0; o < O3_; ++o) acc[o] += (double)av[u] * w[(cq * 4 + u) * 16 + o];
    }
    double* dst = Z + (size_t)m * 16;
#pragma unroll
    for (int o = 0; o < O3_; ++o) dst[o] = acc[o];
}

// ---------------- LIF scan + delay, layers 1/2 (O=512, f64 state) ----------------
__global__ void scan12(const double* __restrict__ Zin,  // [B, T, 512] f64
                       const int* __restrict__ delay,   // [512]
                       float* __restrict__ Sout,        // [B, T, 512] f32 spikes
                       float* __restrict__ sumOut) {
    int blk = blockIdx.x;
    int o = (blk & 7) * 64 + threadIdx.x;
    int b = blk >> 3;
    const double* z = Zin + (size_t)b * T_ * O1_ + o;
    float* s = Sout + (size_t)b * T_ * O1_ + o;
    int d = delay[o];
    for (int t = 0; t < d; ++t) s[(size_t)t * O1_] = 0.f;
    double cur = 0.0, vol = 0.0;
    float cnt = 0.f;
    // 296 = 37*8; tail of 4 handled after.
    for (int t8 = 0; t8 < 296; t8 += 8) {
        double zb[8];
#pragma unroll
        for (int u = 0; u < 8; ++u) zb[u] = z[(size_t)(t8 + u) * O1_];
#pragma unroll
        for (int u = 0; u < 8; ++u) {
            int t = t8 + u;
            cur = cur * 0.75 + zb[u];
            vol = vol * 0.97 + cur;
            float sp = (vol >= 1.25) ? 1.f : 0.f;
            if (sp > 0.f) vol = 0.0;
            int tw = t + d;
            if (tw < T_) { s[(size_t)tw * O1_] = sp; cnt += sp; }
        }
    }
    {
        double zb[4];
#pragma unroll
        for (int u = 0; u < 4; ++u) zb[u] = z[(size_t)(296 + u) * O1_];
#pragma unroll
        for (int u = 0; u < 4; ++u) {
            int t = 296 + u;
            cur = cur * 0.75 + zb[u];
            vol = vol * 0.97 + cur;
            float sp = (vol >= 1.25) ? 1.f : 0.f;
            if (sp > 0.f) vol = 0.0;
            int tw = t + d;
            if (tw < T_) { s[(size_t)tw * O1_] = sp; cnt += sp; }
        }
    }
    for (int off = 32; off; off >>= 1) cnt += __shfl_down(cnt, off);
    if (threadIdx.x == 0) atomicAdd(sumOut, cnt);
}

// ---------------- LIF scan + delay, layer 3 (O=10, f64 state) ----------------
__global__ void scan3(const double* __restrict__ Z3,  // [M, 16] f64
                      const int* __restrict__ d3,     // [10]
                      float* __restrict__ out,        // d_out: [B, 10, 300] f32
                      float* __restrict__ sumOut) {
    __shared__ double zt[T_ * 16];
    int b = blockIdx.x;
    const double2* src = (const double2*)(Z3 + (size_t)b * T_ * 16);
    for (int e = threadIdx.x; e < T_ * 8; e += 64)
        ((double2*)zt)[e] = src[e];
    __syncthreads();
    int o = threadIdx.x;
    if (o < O3_) {
        int d = d3[o];
        float* dst = out + (size_t)b * O3_ * T_ + (size_t)o * T_;
        for (int t = 0; t < d; ++t) dst[t] = 0.f;
        double cur = 0.0, vol = 0.0;
        float cnt = 0.f;
        for (int t = 0; t < T_; ++t) {
            cur = cur * 0.75 + zt[t * 16 + o];
            vol = vol * 0.97 + cur;
            float sp = (vol >= 1.25) ? 1.f : 0.f;
            if (sp > 0.f) vol = 0.0;
            int tw = t + d;
            if (tw < T_) { dst[tw] = sp; cnt += sp; }
        }
        atomicAdd(sumOut, cnt);
    }
}

__global__ void finalize(const float* __restrict__ sums, float* __restrict__ out) {
    if (threadIdx.x == 0) {
        out[0] = (float)((double)sums[0] / (double)(B_ * O1_ * T_));
        out[1] = (float)((double)sums[1] / (double)(B_ * O2_ * T_));
        out[2] = (float)((double)sums[2] / (double)(B_ * O3_ * T_));
    }
}

extern "C" void kernel_launch(void* const* d_in, const int* in_sizes, int n_in,
                              void* d_out, int out_size, void* d_ws, size_t ws_size,
                              hipStream_t stream) {
    const float* spike = (const float*)d_in[0];
    const float* v1 = (const float*)d_in[1];
    const float* g1 = (const float*)d_in[2];
    const float* v2 = (const float*)d_in[3];
    const float* g2 = (const float*)d_in[4];
    const float* v3 = (const float*)d_in[5];
    const float* g3 = (const float*)d_in[6];
    const int* d1 = (const int*)d_in[7];
    const int* d2 = (const int*)d_in[8];
    const int* d3 = (const int*)d_in[9];
    float* out = (float*)d_out;

    // Workspace (same layout as R3-R10 pass): ~72 MB total.
    double* dw = (double*)d_ws;
    size_t off = 0;
    double* f1  = dw + off; off += 512;
    double* f2  = dw + off; off += 512;
    double* f3  = dw + off; off += 16;
    double* Wt1 = dw + off; off += (size_t)C1_ * O1_;
    double* Wt2 = dw + off; off += 512 * 512;
    double* Wt3 = dw + off; off += 512 * 16;
    double* zA  = dw + off; off += (size_t)M_ * 512;
    double* z3b = dw + off; off += (size_t)M_ * 16;
    float* fw = (float*)(dw + off);
    float* sB   = fw;                        // f32 spikes, M*512
    float* sums = fw + (size_t)M_ * 512;     // 4 floats
    (void)ws_size; (void)out_size; (void)in_sizes; (void)n_in;

    hipMemsetAsync(sums, 0, 4 * sizeof(float), stream);

    calc_f<<<512, 256, 0, stream>>>(v1, g1, f1, O1_, C1_);
    calc_f<<<512, 256, 0, stream>>>(v2, g2, f2, O2_, O1_);
    calc_f<<<O3_, 256, 0, stream>>>(v3, g3, f3, O3_, O2_);

    transpose_scale<<<dim3((C1_ + 31) / 32, 16), dim3(32, 8), 0, stream>>>(v1, f1, Wt1, O1_, C1_, O1_);
    transpose_scale<<<dim3(16, 16), dim3(32, 8), 0, stream>>>(v2, f2, Wt2, O2_, O1_, O2_);
    transpose_scale<<<dim3(16, 1), dim3(32, 8), 0, stream>>>(v3, f3, Wt3, O3_, O2_, 16);

    // gemm1: 10 t-chunks(32t) x 4 o-slices(128) x 32 b = 1280 blocks, 5120 indep waves
    gemm1<<<dim3(10, 4, B_), 256, 0, stream>>>(spike, Wt1, zA);       // zA = z1 (f64)
    scan12<<<256, 64, 0, stream>>>(zA, d1, sB, sums + 0);             // sB = s1 (f32)
    // gemm2: 300 m-chunks(32m) x 4 o-slices = 1200 blocks, 4800 indep waves
    gemm2<<<dim3(300, 4), 256, 0, stream>>>(sB, Wt2, zA);             // zA = z2
    scan12<<<256, 64, 0, stream>>>(zA, d2, sB, sums + 1);             // sB = s2
    gemm3<<<(M_ + 255) / 256, 256, 0, stream>>>(sB, Wt3, z3b);        // z3b = z3
    scan3<<<B_, 64, 0, stream>>>(z3b, d3, out, sums + 2);
    finalize<<<1, 64, 0, stream>>>(sums, out + (size_t)B_ * O3_ * T_);
}